// Round 5
// baseline (105.996 us; speedup 1.0000x reference)
//
#include <hip/hip_runtime.h>

#pragma clang fp contract(off)

#define NP 410881  // 641*641

// ---------------------------------------------------------------------------
// Kernel 1: per-slot tables from transformer_class_probs (128 x 134).
// One wave per 8 rows; shuffle-reduce (max, first-index) over 133 cols.
// ---------------------------------------------------------------------------
__global__ __launch_bounds__(1024) void slot_kernel(
    const float* __restrict__ probs, float* __restrict__ cls_pred,
    int* __restrict__ det_idx, unsigned long long* __restrict__ det_mask,
    int* __restrict__ num_det) {
  __shared__ float s_val[128];
  __shared__ int s_arg[128];
  __shared__ int s_tot0;
  int tid = threadIdx.x;
  int wv = tid >> 6, lane = tid & 63;

  float bvv[8];
  int bii[8];
#pragma unroll
  for (int k = 0; k < 8; ++k) {  // preload: 24 outstanding loads per lane
    int r = wv * 8 + k;
    const float* row = probs + r * 134;
    float v0 = row[lane];
    float v1 = row[lane + 64];
    float v2 = (lane < 5) ? row[lane + 128] : -1.0f;
    float bv = v0;
    int bi = lane;
    if (v1 > bv) { bv = v1; bi = lane + 64; }
    if (v2 > bv) { bv = v2; bi = lane + 128; }
    bvv[k] = bv; bii[k] = bi;
  }
#pragma unroll
  for (int k = 0; k < 8; ++k) {
    float bv = bvv[k];
    int bi = bii[k];
#pragma unroll
    for (int off = 32; off; off >>= 1) {  // (max, first-idx) butterfly
      float ov = __shfl_xor(bv, off);
      int oi = __shfl_xor(bi, off);
      if (ov > bv || (ov == bv && oi < bi)) { bv = ov; bi = oi; }
    }
    if (lane == 0) { s_val[wv * 8 + k] = bv; s_arg[wv * 8 + k] = bi; }
  }
  __syncthreads();

  bool flag = false;
  unsigned long long b = 0;
  if (tid < 128) flag = s_val[tid] >= 0.7f;
  if (wv < 2) b = __ballot(flag);  // wave-uniform branch
  if (tid < 128 && lane == 0) {
    det_mask[wv] = b;
    if (wv == 0) s_tot0 = __popcll(b);
  }
  __syncthreads();
  if (tid < 128) {
    int incl = __popcll(b & ((1ull << lane) - 1)) + (flag ? 1 : 0) +
               (wv ? s_tot0 : 0);
    det_idx[tid] = incl - 1;  // cumsum(det)-1
    cls_pred[tid] = (float)s_arg[tid];
    if (tid == 127) *num_det = incl;
  }
}

// ---------------------------------------------------------------------------
// Kernel 2: lanes = pixels, NO LDS AT ALL (round-5 structural change).
// Block of 128 threads covers a 16x16 output region; each lane owns a 1x2
// x-strip inside one bilinear cell. The lane's 4 texel channel-rows are read
// directly from global with float4 loads at loop-invariant base pointers +
// immediate offsets; per wave-load only 8 distinct 16B lines (L1 broadcast).
// No staging prologue, no __syncthreads, no DS pipe: occupancy is
// wave-limited and all latency is hidden by free-running waves.
// 4 independent accumulator streams break the serial max/exp chains.
// ---------------------------------------------------------------------------
__global__ __launch_bounds__(128) void post_kernel(
    const float* __restrict__ logits, const float* __restrict__ ws_cls,
    const int* __restrict__ ws_didx,
    const unsigned long long* __restrict__ ws_mask,
    const int* __restrict__ ws_ndet, float* __restrict__ out) {
#pragma clang fp contract(off)
  int tid = threadIdx.x;
  int X0 = blockIdx.x << 4, Y0 = blockIdx.y << 4;

  // lane -> pixel pair
  int strip = tid & 7, py = tid >> 3;
  int cx = strip >> 1, h = strip & 1;
  int cy = py >> 2;
  int xa = X0 + (cx << 2) + (h << 1);
  int y = Y0 + py;

  int ndet = *ws_ndet;  // uniform
  if (ndet == 0) {      // reference zeroes everything when nothing detected
    if (y < 641) {
      if (xa < 641) {
        int i0 = y * 641 + xa;
        out[i0] = 1.0f; out[NP + i0] = 0.f; out[2 * NP + i0] = 0.f; out[3 * NP + i0] = 0.f;
      }
      if (xa + 1 < 641) {
        int i1 = y * 641 + xa + 1;
        out[i1] = 1.0f; out[NP + i1] = 0.f; out[2 * NP + i1] = 0.f; out[3 * NP + i1] = 0.f;
      }
    }
    return;
  }

  // texel coordinates (clamped; matches reference x1=min(x0+1,160))
  int tx0 = min((X0 >> 2) + cx, 160);
  int tx1 = min(tx0 + 1, 160);
  int ty0 = min((Y0 >> 2) + cy, 160);
  int ty1 = min(ty0 + 1, 160);
  const float* P00 = logits + ((ty0 * 161 + tx0) << 7);
  const float* P01 = logits + ((ty0 * 161 + tx1) << 7);
  const float* P10 = logits + ((ty1 * 161 + tx0) << 7);
  const float* P11 = logits + ((ty1 * 161 + tx1) << 7);

  float wy = 0.25f * (float)(py & 3);
  float iwy = 1.0f - wy;
  float wx0 = 0.5f * (float)h;
  float wx1 = wx0 + 0.25f;
  float iwx0 = 1.0f - wx0, iwx1 = 1.0f - wx1;

  float m0 = -INFINITY, m1 = -INFINITY;  // final masked max
  int am0 = 0, am1 = 0;                  // final masked argmax (first-index)
  float T0 = 0.f, T1 = 0.f;              // final sum exp(v) over detected
  bool dp0 = true, dp1 = true;           // detected_pixel

  if (ndet == 128) {  // fast path: masked == resized
    // 4 independent accumulator streams: stream j = channels c with c&3==j
    float ms0[4], ms1[4], Ts0[4], Ts1[4];
    int as0[4], as1[4];
#pragma unroll
    for (int j = 0; j < 4; ++j) {
      ms0[j] = -INFINITY; ms1[j] = -INFINITY;
      Ts0[j] = 0.f; Ts1[j] = 0.f;
      as0[j] = 0; as1[j] = 0;
    }
// one channel into stream J; reference op order, contract off
#define CH(A00, A01, A10, A11, CIDX, J)                                        \
  {                                                                            \
    float r0 = (A00) * iwy + (A10) * wy;                                       \
    float r1 = (A01) * iwy + (A11) * wy;                                       \
    float v0 = r0 * iwx0 + r1 * wx0;                                           \
    float v1 = r0 * iwx1 + r1 * wx1;                                           \
    bool g0 = v0 > ms0[J]; ms0[J] = g0 ? v0 : ms0[J]; as0[J] = g0 ? (CIDX) : as0[J]; \
    bool g1 = v1 > ms1[J]; ms1[J] = g1 ? v1 : ms1[J]; as1[J] = g1 ? (CIDX) : as1[J]; \
    Ts0[J] += __expf(v0);                                                      \
    Ts1[J] += __expf(v1);                                                      \
  }
#pragma unroll 4
    for (int c = 0; c < 128; c += 4) {
      float4 q00 = *(const float4*)(P00 + c);
      float4 q01 = *(const float4*)(P01 + c);
      float4 q10 = *(const float4*)(P10 + c);
      float4 q11 = *(const float4*)(P11 + c);
      CH(q00.x, q01.x, q10.x, q11.x, c + 0, 0);
      CH(q00.y, q01.y, q10.y, q11.y, c + 1, 1);
      CH(q00.z, q01.z, q10.z, q11.z, c + 2, 2);
      CH(q00.w, q01.w, q10.w, q11.w, c + 3, 3);
    }
#undef CH
    // exact merge: global max; on value tie, smallest channel index wins
    m0 = ms0[0]; am0 = as0[0]; m1 = ms1[0]; am1 = as1[0];
#pragma unroll
    for (int j = 1; j < 4; ++j) {
      if (ms0[j] > m0 || (ms0[j] == m0 && as0[j] < am0)) { m0 = ms0[j]; am0 = as0[j]; }
      if (ms1[j] > m1 || (ms1[j] == m1 && as1[j] < am1)) { m1 = ms1[j]; am1 = as1[j]; }
    }
    T0 = (Ts0[0] + Ts0[1]) + (Ts0[2] + Ts0[3]);
    T1 = (Ts1[0] + Ts1[1]) + (Ts1[2] + Ts1[3]);
  } else {  // general: separate raw max; per-channel detection is uniform
    unsigned long long mlo = ws_mask[0], mhi = ws_mask[1];
    float rm0 = -INFINITY, rm1 = -INFINITY;
#pragma unroll 4
    for (int c = 0; c < 128; ++c) {
      float a00 = P00[c], a01 = P01[c];
      float a10 = P10[c], a11 = P11[c];
      float r0 = a00 * iwy + a10 * wy;
      float r1 = a01 * iwy + a11 * wy;
      float v0 = r0 * iwx0 + r1 * wx0;
      float v1 = r0 * iwx1 + r1 * wx1;
      rm0 = fmaxf(rm0, v0);
      rm1 = fmaxf(rm1, v1);
      unsigned long long bit = (c < 64) ? (mlo >> c) : (mhi >> (c - 64));
      if (bit & 1) {  // scalar branch (wave-uniform)
        bool g0 = v0 > m0; m0 = g0 ? v0 : m0; am0 = g0 ? c : am0;
        bool g1 = v1 > m1; m1 = g1 ? v1 : m1; am1 = g1 ? c : am1;
        T0 += __expf(v0);
        T1 += __expf(v1);
      }
    }
    dp0 = (rm0 == m0);
    dp1 = (rm1 == m1);
  }

  // ---- epilogue: conf > 0.4  <=>  exp(m) > 0.4*T  (T > 0, all v bounded)
  float cg0 = ((__expf(m0) > 0.4f * T0) && dp0) ? 1.0f : 0.0f;
  float cg1 = ((__expf(m1) > 0.4f * T1) && dp1) ? 1.0f : 0.0f;
  float sem0 = ws_cls[am0], sem1 = ws_cls[am1];  // L1/L2-cached 128-entry tables
  float mid0 = (float)(ws_didx[am0] + 1), mid1 = (float)(ws_didx[am1] + 1);
  float th0 = (sem0 < 80.f) ? cg0 : 0.f;
  float st0 = cg0 - th0;
  float th1 = (sem1 < 80.f) ? cg1 : 0.f;
  float st1 = cg1 - th1;

  if (y < 641) {
    if (xa < 641) {
      int i0 = y * 641 + xa;
      out[i0] = mid0; out[NP + i0] = sem0; out[2 * NP + i0] = th0; out[3 * NP + i0] = st0;
    }
    if (xa + 1 < 641) {
      int i1 = y * 641 + xa + 1;
      out[i1] = mid1; out[NP + i1] = sem1; out[2 * NP + i1] = th1; out[3 * NP + i1] = st1;
    }
  }
}

extern "C" void kernel_launch(void* const* d_in, const int* in_sizes, int n_in,
                              void* d_out, int out_size, void* d_ws,
                              size_t ws_size, hipStream_t stream) {
  const float* logits = (const float*)d_in[0];  // (161,161,128) f32
  const float* probs = (const float*)d_in[1];   // (128,134) f32
  float* out = (float*)d_out;

  float* ws_f = (float*)d_ws;
  float* cls_pred = ws_f;                                    // 128 f32
  int* det_idx = (int*)(ws_f + 128);                         // 128 i32
  unsigned long long* det_mask = (unsigned long long*)(ws_f + 256);  // 2 u64
  int* num_det = (int*)(ws_f + 260);                         // 1 i32

  slot_kernel<<<1, 1024, 0, stream>>>(probs, cls_pred, det_idx, det_mask,
                                      num_det);

  dim3 grid(41, 41);
  post_kernel<<<grid, 128, 0, stream>>>(logits, cls_pred, det_idx, det_mask,
                                        num_det, out);
}

// Round 6
// 97.499 us; speedup vs baseline: 1.0871x; 1.0871x over previous
//
#include <hip/hip_runtime.h>

#pragma clang fp contract(off)

#define NP 410881  // 641*641

// ---------------------------------------------------------------------------
// Kernel 1: per-slot tables from transformer_class_probs (128 x 134).
// One wave per 8 rows; shuffle-reduce (max, first-index) over 133 cols.
// ---------------------------------------------------------------------------
__global__ __launch_bounds__(1024) void slot_kernel(
    const float* __restrict__ probs, float* __restrict__ cls_pred,
    int* __restrict__ det_idx, unsigned long long* __restrict__ det_mask,
    int* __restrict__ num_det) {
  __shared__ float s_val[128];
  __shared__ int s_arg[128];
  __shared__ int s_tot0;
  int tid = threadIdx.x;
  int wv = tid >> 6, lane = tid & 63;

  float bvv[8];
  int bii[8];
#pragma unroll
  for (int k = 0; k < 8; ++k) {  // preload: 24 outstanding loads per lane
    int r = wv * 8 + k;
    const float* row = probs + r * 134;
    float v0 = row[lane];
    float v1 = row[lane + 64];
    float v2 = (lane < 5) ? row[lane + 128] : -1.0f;
    float bv = v0;
    int bi = lane;
    if (v1 > bv) { bv = v1; bi = lane + 64; }
    if (v2 > bv) { bv = v2; bi = lane + 128; }
    bvv[k] = bv; bii[k] = bi;
  }
#pragma unroll
  for (int k = 0; k < 8; ++k) {
    float bv = bvv[k];
    int bi = bii[k];
#pragma unroll
    for (int off = 32; off; off >>= 1) {  // (max, first-idx) butterfly
      float ov = __shfl_xor(bv, off);
      int oi = __shfl_xor(bi, off);
      if (ov > bv || (ov == bv && oi < bi)) { bv = ov; bi = oi; }
    }
    if (lane == 0) { s_val[wv * 8 + k] = bv; s_arg[wv * 8 + k] = bi; }
  }
  __syncthreads();

  bool flag = false;
  unsigned long long b = 0;
  if (tid < 128) flag = s_val[tid] >= 0.7f;
  if (wv < 2) b = __ballot(flag);  // wave-uniform branch
  if (tid < 128 && lane == 0) {
    det_mask[wv] = b;
    if (wv == 0) s_tot0 = __popcll(b);
  }
  __syncthreads();
  if (tid < 128) {
    int incl = __popcll(b & ((1ull << lane) - 1)) + (flag ? 1 : 0) +
               (wv ? s_tot0 : 0);
    det_idx[tid] = incl - 1;  // cumsum(det)-1
    cls_pred[tid] = (float)s_arg[tid];
    if (tid == 127) *num_det = incl;
  }
}

// ---------------------------------------------------------------------------
// Kernel 2 (round 6): OCCUPANCY restructure. Rounds 2-5 all plateaued at
// ~35-44 us because 2 px/lane gives only ~3362 waves = 13/CU (3.3/SIMD) --
// latency-bound regardless of inner-loop form. Now: 1 pixel per thread,
// channels split across thread pairs (half = 64 channels). Block = 512
// threads (8 waves) covers a 16x16 region; ~6724 waves total -> residency
// capped by HW (24-32 waves/CU), not by the grid. Halves merge per-pixel
// via 4 KB LDS + one __syncthreads.
// ---------------------------------------------------------------------------
__global__ __launch_bounds__(512) void post_kernel(
    const float* __restrict__ logits, const float* __restrict__ ws_cls,
    const int* __restrict__ ws_didx,
    const unsigned long long* __restrict__ ws_mask,
    const int* __restrict__ ws_ndet, float* __restrict__ out) {
#pragma clang fp contract(off)
  __shared__ float sm[256], sT[256], srm[256];
  __shared__ int sa[256];

  int t = threadIdx.x;
  int p = t & 255;    // pixel index in 16x16 region
  int half = t >> 8;  // channel half: 0 -> ch 0..63, 1 -> ch 64..127
  int X0 = blockIdx.x << 4, Y0 = blockIdx.y << 4;
  int x = X0 + (p & 15);
  int y = Y0 + (p >> 4);
  bool valid = (x < 641) && (y < 641);
  int xc = min(x, 640), yc = min(y, 640);

  int ndet = *ws_ndet;  // uniform
  if (ndet == 0) {      // reference zeroes everything when nothing detected
    if (valid && half == 0) {
      int i0 = y * 641 + x;
      out[i0] = 1.0f; out[NP + i0] = 0.f; out[2 * NP + i0] = 0.f; out[3 * NP + i0] = 0.f;
    }
    return;
  }

  // texel coords + weights (scale exactly 1/4; matches reference exactly)
  int tx0 = xc >> 2, ty0 = yc >> 2;
  int tx1 = min(tx0 + 1, 160), ty1 = min(ty0 + 1, 160);
  float wx = 0.25f * (float)(xc & 3), iwx = 1.0f - wx;
  float wy = 0.25f * (float)(yc & 3), iwy = 1.0f - wy;

  int co = half << 6;  // channel offset of this half
  const float* P00 = logits + ((ty0 * 161 + tx0) << 7) + co;
  const float* P01 = logits + ((ty0 * 161 + tx1) << 7) + co;
  const float* P10 = logits + ((ty1 * 161 + tx0) << 7) + co;
  const float* P11 = logits + ((ty1 * 161 + tx1) << 7) + co;

  float m = -INFINITY;  // this half's masked max
  int am = 0;           // this half's masked argmax (global channel id)
  float T = 0.f;        // this half's sum exp(v) over detected
  float rm = -INFINITY; // this half's raw max

  if (ndet == 128) {  // fast path: masked == resized
    // 4 independent streams break the serial max/exp chains
    float ms[4], Ts[4];
    int as[4];
#pragma unroll
    for (int j = 0; j < 4; ++j) { ms[j] = -INFINITY; Ts[j] = 0.f; as[j] = 0; }
// one channel into stream J; reference op order, contract off
#define CH(A00, A01, A10, A11, CIDX, J)                                        \
  {                                                                            \
    float r0 = (A00) * iwy + (A10) * wy;                                       \
    float r1 = (A01) * iwy + (A11) * wy;                                       \
    float v = r0 * iwx + r1 * wx;                                              \
    bool g = v > ms[J]; ms[J] = g ? v : ms[J]; as[J] = g ? (CIDX) : as[J];     \
    Ts[J] += __expf(v);                                                        \
  }
#pragma unroll 2
    for (int c = 0; c < 64; c += 4) {
      float4 q00 = *(const float4*)(P00 + c);
      float4 q01 = *(const float4*)(P01 + c);
      float4 q10 = *(const float4*)(P10 + c);
      float4 q11 = *(const float4*)(P11 + c);
      CH(q00.x, q01.x, q10.x, q11.x, co + c + 0, 0);
      CH(q00.y, q01.y, q10.y, q11.y, co + c + 1, 1);
      CH(q00.z, q01.z, q10.z, q11.z, co + c + 2, 2);
      CH(q00.w, q01.w, q10.w, q11.w, co + c + 3, 3);
    }
#undef CH
    // exact merge: global max; on value tie, smallest channel index wins
    m = ms[0]; am = as[0];
#pragma unroll
    for (int j = 1; j < 4; ++j)
      if (ms[j] > m || (ms[j] == m && as[j] < am)) { m = ms[j]; am = as[j]; }
    T = (Ts[0] + Ts[1]) + (Ts[2] + Ts[3]);
    rm = m;
  } else {  // general path (never taken for this input; correctness only)
    unsigned long long msk = ws_mask[half];
#pragma unroll 4
    for (int c = 0; c < 64; ++c) {
      float a00 = P00[c], a01 = P01[c];
      float a10 = P10[c], a11 = P11[c];
      float r0 = a00 * iwy + a10 * wy;
      float r1 = a01 * iwy + a11 * wy;
      float v = r0 * iwx + r1 * wx;
      rm = fmaxf(rm, v);
      if ((msk >> c) & 1) {  // wave-uniform branch
        bool g = v > m; m = g ? v : m; am = g ? (co + c) : am;
        T += __expf(v);
      }
    }
  }

  // ---- cross-half merge via LDS ----
  if (half == 1) { sm[p] = m; sa[p] = am; sT[p] = T; srm[p] = rm; }
  __syncthreads();
  if (half == 0) {
    float m1 = sm[p], T1 = sT[p], rm1 = srm[p];
    int a1 = sa[p];
    if (m1 > m || (m1 == m && a1 < am)) { m = m1; am = a1; }
    T += T1;
    rm = fmaxf(rm, rm1);
    bool dp = (rm == m);  // detected_pixel: full_max == det_max (exact)

    // conf > 0.4  <=>  exp(m) > 0.4*T  (T > 0, |v| bounded)
    float cg = ((__expf(m) > 0.4f * T) && dp) ? 1.0f : 0.0f;
    float sem = ws_cls[am];
    float mid = (float)(ws_didx[am] + 1);
    float th = (sem < 80.f) ? cg : 0.f;
    float st = cg - th;
    if (valid) {
      int i0 = y * 641 + x;
      out[i0] = mid; out[NP + i0] = sem; out[2 * NP + i0] = th; out[3 * NP + i0] = st;
    }
  }
}

extern "C" void kernel_launch(void* const* d_in, const int* in_sizes, int n_in,
                              void* d_out, int out_size, void* d_ws,
                              size_t ws_size, hipStream_t stream) {
  const float* logits = (const float*)d_in[0];  // (161,161,128) f32
  const float* probs = (const float*)d_in[1];   // (128,134) f32
  float* out = (float*)d_out;

  float* ws_f = (float*)d_ws;
  float* cls_pred = ws_f;                                    // 128 f32
  int* det_idx = (int*)(ws_f + 128);                         // 128 i32
  unsigned long long* det_mask = (unsigned long long*)(ws_f + 256);  // 2 u64
  int* num_det = (int*)(ws_f + 260);                         // 1 i32

  slot_kernel<<<1, 1024, 0, stream>>>(probs, cls_pred, det_idx, det_mask,
                                      num_det);

  dim3 grid(41, 41);
  post_kernel<<<grid, 512, 0, stream>>>(logits, cls_pred, det_idx, det_mask,
                                        num_det, out);
}